// Round 5
// baseline (226.466 us; speedup 1.0000x reference)
//
#include <hip/hip_runtime.h>
#include <hip/hip_bf16.h>

#define BATCH 64
#define CCH 128
#define SEQ 1024
#define NG 32
#define EPSV 1e-6f
#define SCALEV 0.044194173824159216f

typedef short v8s __attribute__((ext_vector_type(8)));
typedef float v4f __attribute__((ext_vector_type(4)));

__device__ __forceinline__ unsigned short f2bf(float f) {
    __hip_bfloat16 h = __float2bfloat16(f);
    return *reinterpret_cast<unsigned short*>(&h);
}

#define MFMA16(a, b, c) __builtin_amdgcn_mfma_f32_16x16x32_bf16(a, b, c, 0, 0, 0)

// async global->LDS, 16B per lane; LDS dst = base + lane*16 (wave-uniform base)
__device__ __forceinline__ void gld_lds16(const unsigned short* g, unsigned short* l) {
    __builtin_amdgcn_global_load_lds(
        (const __attribute__((address_space(1))) void*)g,
        (__attribute__((address_space(3))) void*)l, 16, 0, 0);
}

// ---------------- weights fp32 -> bf16 ----------------
__global__ void prep_weights(const float* wq, const float* wk, const float* wv,
                             const float* wo, unsigned short* wbf) {
    int i = blockIdx.x * 256 + threadIdx.x;     // 0..65535
    const float* srcs[4] = {wq, wk, wv, wo};
    int m = i >> 14;
    int j = i & 16383;
    wbf[i] = f2bf(srcs[m][j]);
}

// ---------------- GroupNorm stats: one block per (b,g) ----------------
__global__ void gn_stats(const float* __restrict__ x, float* meanr, float* rstdr) {
    int bg = blockIdx.x;                         // b*NG + g
    const float4* p = (const float4*)(x + (size_t)bg * (4 * SEQ));
    int tid = threadIdx.x;
    float s1 = 0.f, s2 = 0.f;
    #pragma unroll
    for (int i = 0; i < 4; i++) {
        float4 v = p[i * 256 + tid];
        s1 += v.x + v.y + v.z + v.w;
        s2 += v.x * v.x + v.y * v.y + v.z * v.z + v.w * v.w;
    }
    #pragma unroll
    for (int off = 32; off; off >>= 1) {
        s1 += __shfl_down(s1, off);
        s2 += __shfl_down(s2, off);
    }
    __shared__ float a1[4], a2[4];
    int w = tid >> 6, l = tid & 63;
    if (l == 0) { a1[w] = s1; a2[w] = s2; }
    __syncthreads();
    if (tid == 0) {
        float t1 = a1[0] + a1[1] + a1[2] + a1[3];
        float t2 = a2[0] + a2[1] + a2[2] + a2[3];
        float mean = t1 * (1.0f / (4 * SEQ));
        float var  = t2 * (1.0f / (4 * SEQ)) - mean * mean;
        meanr[bg] = mean;
        rstdr[bg] = rsqrtf(var + EPSV);
    }
}

// ---------------- fused GroupNorm-apply + QKV projection ----------------
// grid: 8 s-tiles x 64 batches; block 256 (4 waves); tile 128 rows x 128 cols.
// All three outputs routed through the LDS tile -> 16B coalesced stores.
__global__ __launch_bounds__(256) void qkv_kernel(
    const float* __restrict__ x, const float* __restrict__ gn_w,
    const float* __restrict__ gn_b, const float* __restrict__ meanr,
    const float* __restrict__ rstdr, const unsigned short* __restrict__ wbf,
    const float* __restrict__ bq, const float* __restrict__ bk,
    const float* __restrict__ bv,
    unsigned short* Q, unsigned short* K, unsigned short* Vt)
{
    __shared__ unsigned short tls[128 * 136];    // pitch 136 shorts (16B-mult)
    int bx = blockIdx.x & 7;
    int b  = blockIdx.x >> 3;
    int s0 = bx * 128;
    int tid = threadIdx.x;
    const float* xb = x + (size_t)b * CCH * SEQ;

    // load x tile, normalize, write t[s][c] bf16 to LDS
    for (int rep = 0; rep < 64; rep++) {
        int idx = rep * 256 + tid;
        int c = idx >> 7, s = idx & 127;
        float v = xb[c * SEQ + s0 + s];
        int g = c >> 2;
        float t = (v - meanr[b * NG + g]) * rstdr[b * NG + g] * gn_w[c] + gn_b[c];
        tls[s * 136 + c] = f2bf(t);
    }
    __syncthreads();

    int w = tid >> 6, lane = tid & 63;
    int m = lane & 15, quad = lane >> 4;

    v8s a[2][4];
    #pragma unroll
    for (int st = 0; st < 2; st++)
        #pragma unroll
        for (int ch = 0; ch < 4; ch++)
            a[st][ch] = *(const v8s*)&tls[(w * 32 + st * 16 + m) * 136 + ch * 32 + quad * 8];
    __syncthreads();   // all frags read; tls reusable

    #pragma unroll
    for (int o = 0; o < 3; o++) {
        const unsigned short* wmat = wbf + o * 16384;
        const float* bias = (o == 0) ? bq : (o == 1) ? bk : bv;
        #pragma unroll
        for (int ct = 0; ct < 8; ct++) {
            v4f acc0 = {0,0,0,0}, acc1 = {0,0,0,0};
            #pragma unroll
            for (int ch = 0; ch < 4; ch++) {
                v8s bfr = *(const v8s*)&wmat[(ct * 16 + m) * 128 + ch * 32 + quad * 8];
                acc0 = MFMA16(a[0][ch], bfr, acc0);
                acc1 = MFMA16(a[1][ch], bfr, acc1);
            }
            int col = ct * 16 + m;
            float bcol = bias[col];
            if (o < 2) {
                // Q/K: [s][c] layout in LDS
                #pragma unroll
                for (int r = 0; r < 4; r++) {
                    int row0 = w * 32 + quad * 4 + r;
                    tls[row0 * 136 + col]        = f2bf(acc0[r] + bcol);
                    tls[(row0 + 16) * 136 + col] = f2bf(acc1[r] + bcol);
                }
            } else {
                // V: transposed [c][s] layout
                #pragma unroll
                for (int r = 0; r < 4; r++) {
                    int row0 = w * 32 + quad * 4 + r;
                    tls[col * 136 + row0]      = f2bf(acc0[r] + bcol);
                    tls[col * 136 + row0 + 16] = f2bf(acc1[r] + bcol);
                }
            }
        }
        __syncthreads();                         // tile complete in LDS
        if (o < 2) {
            unsigned short* dst = (o == 0 ? Q : K) + (size_t)b * SEQ * CCH;
            #pragma unroll
            for (int rep = 0; rep < 8; rep++) {
                int idx = rep * 256 + tid;
                int row = idx >> 4, chunk = idx & 15;
                *(v8s*)&dst[(size_t)(s0 + row) * 128 + chunk * 8] =
                    *(const v8s*)&tls[row * 136 + chunk * 8];
            }
        } else {
            unsigned short* vdst = Vt + (size_t)b * CCH * SEQ;
            #pragma unroll
            for (int rep = 0; rep < 8; rep++) {
                int idx = rep * 256 + tid;
                int c = idx >> 4, chunk = idx & 15;
                *(v8s*)&vdst[(size_t)c * SEQ + s0 + chunk * 8] =
                    *(const v8s*)&tls[c * 136 + chunk * 8];
            }
        }
        __syncthreads();                         // stores done before reuse
    }
}

// ---------------- flash attention: LDS-staged K/V, no-max softmax ----------
// grid: 1024 blocks = 64 batches x 16 q-tiles of 64 rows; XCD-swizzled so each
// XCD owns 8 batches (K+V = 4MB = its L2). Block 256 (4 waves); wave owns 16
// Q rows. K (64x128) and V (128x64) tiles staged per block via global_load_lds
// (XOR-chunk swizzle: staging lane-contiguous, frag reads bank-balanced);
// 41KB LDS -> 3 blocks/CU resident, blocks out of phase cover barrier drains.
__global__ __launch_bounds__(256, 3) void attn_kernel(
    const unsigned short* __restrict__ Q, const unsigned short* __restrict__ K,
    const unsigned short* __restrict__ Vt, unsigned short* O)
{
    __shared__ unsigned short klds[64 * 128];    // [key][ch], chunk^=(key&15)
    __shared__ unsigned short vlds[128 * 64];    // [ch][t],  chunk^=(ch&7)
    __shared__ unsigned short plds[4][16 * 72];  // per-wave P, pitch 72 shorts
    int i = blockIdx.x;
    int b  = (i & 7) * 8 + ((i >> 3) & 7);       // 8 batches per XCD
    int qt = i >> 6;                             // 0..15
    int tid = threadIdx.x;
    int w = tid >> 6, lane = tid & 63;
    int m = lane & 15, quad = lane >> 4;
    int qrow0 = qt * 64 + w * 16;
    const unsigned short* Qb = Q + (size_t)b * SEQ * CCH;
    const unsigned short* Kb = K + (size_t)b * SEQ * CCH;
    const unsigned short* Vb = Vt + (size_t)b * CCH * SEQ;
    unsigned short* pw = plds[w];

    v8s aq[4];
    #pragma unroll
    for (int ch = 0; ch < 4; ch++)
        aq[ch] = *(const v8s*)&Qb[(size_t)(qrow0 + m) * 128 + ch * 32 + quad * 8];

    v4f oacc[8];
    #pragma unroll
    for (int ct = 0; ct < 8; ct++) oacc[ct] = (v4f){0, 0, 0, 0};
    float lrun[4] = {0.f, 0.f, 0.f, 0.f};

    int krow_off = lane >> 4;                    // K staging: 4 rows per inst
    int kchunk_l = lane & 15;
    int vch_off  = lane >> 3;                    // V staging: 8 ch-rows per inst
    int vchunk_l = lane & 7;

    for (int kt = 0; kt < 16; kt++) {
        int t0 = kt * 64;
        __syncthreads();                         // prev tile fully consumed
        #pragma unroll
        for (int j4 = 0; j4 < 4; j4++) {
            int j = w * 4 + j4;
            int kr = 4 * j + krow_off;
            int kc = kchunk_l ^ (kr & 15);
            gld_lds16(Kb + (size_t)(t0 + kr) * 128 + kc * 8, klds + j * 512);
            int vc = 8 * j + vch_off;
            int vk = vchunk_l ^ (vc & 7);
            gld_lds16(Vb + (size_t)vc * SEQ + t0 + vk * 8, vlds + j * 512);
        }
        __syncthreads();                         // staging complete

        // ---- QK^T: 4 key 16-tiles ----
        #pragma unroll
        for (int c2 = 0; c2 < 4; c2++) {
            int krow = c2 * 16 + m;
            v4f acc = {0,0,0,0};
            #pragma unroll
            for (int ch = 0; ch < 4; ch++) {
                int chunk = (ch * 4 + quad) ^ (krow & 15);
                v8s kb = *(const v8s*)&klds[krow * 128 + chunk * 8];
                acc = MFMA16(aq[ch], kb, acc);
            }
            #pragma unroll
            for (int r = 0; r < 4; r++) {
                float p = __expf(acc[r] * SCALEV);
                lrun[r] += p;
                pw[(quad * 4 + r) * 72 + c2 * 16 + m] = f2bf(p);
            }
        }
        // ---- P: C-layout -> A-frags (wave-local LDS, in-order) ----
        v8s pa0 = *(const v8s*)&pw[m * 72 + quad * 8];
        v8s pa1 = *(const v8s*)&pw[m * 72 + 32 + quad * 8];
        // ---- PV: 8 out-col tiles x 2 k-chunks ----
        #pragma unroll
        for (int ct = 0; ct < 8; ct++) {
            int vrow = ct * 16 + m;
            int ck0 = quad ^ (vrow & 7);
            int ck1 = (4 + quad) ^ (vrow & 7);
            oacc[ct] = MFMA16(pa0, *(const v8s*)&vlds[vrow * 64 + ck0 * 8], oacc[ct]);
            oacc[ct] = MFMA16(pa1, *(const v8s*)&vlds[vrow * 64 + ck1 * 8], oacc[ct]);
        }
    }
    // ---- final row-sum reduction over the 16-lane m-group (once) ----
    float inv[4];
    #pragma unroll
    for (int r = 0; r < 4; r++) {
        float rs = lrun[r];
        rs += __shfl_xor(rs, 1);
        rs += __shfl_xor(rs, 2);
        rs += __shfl_xor(rs, 4);
        rs += __shfl_xor(rs, 8);
        inv[r] = 1.0f / rs;
    }
    unsigned short* Ob = O + (size_t)b * SEQ * CCH;
    #pragma unroll
    for (int ct = 0; ct < 8; ct++)
        #pragma unroll
        for (int r = 0; r < 4; r++)
            Ob[(size_t)(qrow0 + quad * 4 + r) * 128 + ct * 16 + m] =
                f2bf(oacc[ct][r] * inv[r]);
}

// ---------------- out projection (transposed) + bias + residual -------------
// Computes out^T = wo @ O^T so MFMA D columns = s -> direct coalesced fp32
// stores to out[b][c][s] with residual read at identical addresses. No LDS.
// grid: 1024 = 64 batches x 16 s-tiles of 64; wave w handles s-strip of 16.
__global__ __launch_bounds__(256) void outproj_kernel(
    const unsigned short* __restrict__ O, const unsigned short* __restrict__ wbo,
    const float* __restrict__ bo, const float* __restrict__ x, float* out)
{
    int bx = blockIdx.x & 15;
    int b  = blockIdx.x >> 4;
    int tid = threadIdx.x;
    int w = tid >> 6, lane = tid & 63;
    int m = lane & 15, quad = lane >> 4;
    int scol = bx * 64 + w * 16;                 // wave's 16 s columns
    const unsigned short* Ob = O + (size_t)b * SEQ * CCH;
    const float* xb = x + (size_t)b * CCH * SEQ;
    float* ob = out + (size_t)b * CCH * SEQ;

    // B-frags: O^T, k=out-channel contiguous
    v8s vb[4];
    #pragma unroll
    for (int ch = 0; ch < 4; ch++)
        vb[ch] = *(const v8s*)&Ob[(size_t)(scol + m) * 128 + ch * 32 + quad * 8];

    #pragma unroll
    for (int mt = 0; mt < 8; mt++) {
        v4f acc = {0,0,0,0};
        #pragma unroll
        for (int ch = 0; ch < 4; ch++) {
            v8s af = *(const v8s*)&wbo[(mt * 16 + m) * 128 + ch * 32 + quad * 8];
            acc = MFMA16(af, vb[ch], acc);
        }
        #pragma unroll
        for (int r = 0; r < 4; r++) {
            int c = mt * 16 + quad * 4 + r;
            int idx = c * SEQ + scol + m;
            ob[idx] = acc[r] + bo[c] + xb[idx];
        }
    }
}

extern "C" void kernel_launch(void* const* d_in, const int* in_sizes, int n_in,
                              void* d_out, int out_size, void* d_ws, size_t ws_size,
                              hipStream_t stream) {
    const float* x    = (const float*)d_in[0];
    const float* gn_w = (const float*)d_in[1];
    const float* gn_b = (const float*)d_in[2];
    const float* wq   = (const float*)d_in[3];
    const float* bq   = (const float*)d_in[4];
    const float* wk   = (const float*)d_in[5];
    const float* bk   = (const float*)d_in[6];
    const float* wv   = (const float*)d_in[7];
    const float* bv   = (const float*)d_in[8];
    const float* wo   = (const float*)d_in[9];
    const float* bo   = (const float*)d_in[10];
    float* out = (float*)d_out;

    char* ws = (char*)d_ws;
    unsigned short* wbf   = (unsigned short*)ws;
    float* meanr          = (float*)(ws + 131072);
    float* rstdr          = (float*)(ws + 139264);
    unsigned short* Qbuf  = (unsigned short*)(ws + 147456);
    unsigned short* Kbuf  = (unsigned short*)(ws + 147456 + 16777216ull);
    unsigned short* Vtbuf = (unsigned short*)(ws + 147456 + 2ull * 16777216ull);
    unsigned short* Obuf  = Qbuf;  // safe alias: attn block reads only its own
                                   // 64 Q rows (into regs, at start) and
                                   // writes the same 64 O rows (at end)

    prep_weights<<<256, 256, 0, stream>>>(wq, wk, wv, wo, wbf);
    gn_stats<<<BATCH * NG, 256, 0, stream>>>(x, meanr, rstdr);
    qkv_kernel<<<BATCH * 8, 256, 0, stream>>>(x, gn_w, gn_b, meanr, rstdr, wbf,
                                              bq, bk, bv, Qbuf, Kbuf, Vtbuf);
    attn_kernel<<<1024, 256, 0, stream>>>(Qbuf, Kbuf, Vtbuf, Obuf);
    outproj_kernel<<<1024, 256, 0, stream>>>(Obuf, wbf + 3 * 16384, bo, x, out);
}

// Round 6
// 208.287 us; speedup vs baseline: 1.0873x; 1.0873x over previous
//
#include <hip/hip_runtime.h>
#include <hip/hip_bf16.h>

#define BATCH 64
#define CCH 128
#define SEQ 1024
#define NG 32
#define EPSV 1e-6f
#define SCALEV 0.044194173824159216f

typedef short v8s __attribute__((ext_vector_type(8)));
typedef float v4f __attribute__((ext_vector_type(4)));
typedef unsigned short us;

__device__ __forceinline__ us f2bf(float f) {
    __hip_bfloat16 h = __float2bfloat16(f);
    return *reinterpret_cast<us*>(&h);
}

#define MFMA16(a, b, c) __builtin_amdgcn_mfma_f32_16x16x32_bf16(a, b, c, 0, 0, 0)

// async global->LDS, 16B per lane; LDS dst = base + lane*16 (wave-uniform base)
__device__ __forceinline__ void gld_lds16(const us* g, us* l) {
    __builtin_amdgcn_global_load_lds(
        (const __attribute__((address_space(1))) void*)g,
        (__attribute__((address_space(3))) void*)l, 16, 0, 0);
}

// ---------------- fused: weights fp32->bf16 (blocks 0..255) + GN stats ------
__global__ void prep_gn(const float* __restrict__ wq, const float* __restrict__ wk,
                        const float* __restrict__ wv, const float* __restrict__ wo,
                        us* wbf, const float* __restrict__ x,
                        float* meanr, float* rstdr) {
    int tid = threadIdx.x;
    if (blockIdx.x < 256) {
        int i = blockIdx.x * 256 + tid;          // 0..65535
        const float* srcs[4] = {wq, wk, wv, wo};
        wbf[i] = f2bf(srcs[i >> 14][i & 16383]);
        return;
    }
    int bg = blockIdx.x - 256;                   // b*NG + g, 0..2047
    const float4* p = (const float4*)(x + (size_t)bg * (4 * SEQ));
    float s1 = 0.f, s2 = 0.f;
    #pragma unroll
    for (int i = 0; i < 4; i++) {
        float4 v = p[i * 256 + tid];
        s1 += v.x + v.y + v.z + v.w;
        s2 += v.x * v.x + v.y * v.y + v.z * v.z + v.w * v.w;
    }
    #pragma unroll
    for (int off = 32; off; off >>= 1) {
        s1 += __shfl_down(s1, off);
        s2 += __shfl_down(s2, off);
    }
    __shared__ float a1[4], a2[4];
    int w = tid >> 6, l = tid & 63;
    if (l == 0) { a1[w] = s1; a2[w] = s2; }
    __syncthreads();
    if (tid == 0) {
        float t1 = a1[0] + a1[1] + a1[2] + a1[3];
        float t2 = a2[0] + a2[1] + a2[2] + a2[3];
        float mean = t1 * (1.0f / (4 * SEQ));
        float var  = t2 * (1.0f / (4 * SEQ)) - mean * mean;
        meanr[bg] = mean;
        rstdr[bg] = rsqrtf(var + EPSV);
    }
}

// ---------------- fused GroupNorm-apply + QKV projection ----------------
// grid: 8 s-tiles x 64 batches; block 256 (4 waves); tile 128 rows x 128 cols.
// All three outputs routed through the LDS tile -> 16B coalesced stores.
__global__ __launch_bounds__(256) void qkv_kernel(
    const float* __restrict__ x, const float* __restrict__ gn_w,
    const float* __restrict__ gn_b, const float* __restrict__ meanr,
    const float* __restrict__ rstdr, const us* __restrict__ wbf,
    const float* __restrict__ bq, const float* __restrict__ bk,
    const float* __restrict__ bv,
    us* Q, us* K, us* Vt)
{
    __shared__ us tls[128 * 136];                // pitch 136 shorts (16B-mult)
    int bx = blockIdx.x & 7;
    int b  = blockIdx.x >> 3;
    int s0 = bx * 128;
    int tid = threadIdx.x;
    const float* xb = x + (size_t)b * CCH * SEQ;

    for (int rep = 0; rep < 64; rep++) {
        int idx = rep * 256 + tid;
        int c = idx >> 7, s = idx & 127;
        float v = xb[c * SEQ + s0 + s];
        int g = c >> 2;
        float t = (v - meanr[b * NG + g]) * rstdr[b * NG + g] * gn_w[c] + gn_b[c];
        tls[s * 136 + c] = f2bf(t);
    }
    __syncthreads();

    int w = tid >> 6, lane = tid & 63;
    int m = lane & 15, quad = lane >> 4;

    v8s a[2][4];
    #pragma unroll
    for (int st = 0; st < 2; st++)
        #pragma unroll
        for (int ch = 0; ch < 4; ch++)
            a[st][ch] = *(const v8s*)&tls[(w * 32 + st * 16 + m) * 136 + ch * 32 + quad * 8];
    __syncthreads();

    #pragma unroll
    for (int o = 0; o < 3; o++) {
        const us* wmat = wbf + o * 16384;
        const float* bias = (o == 0) ? bq : (o == 1) ? bk : bv;
        #pragma unroll
        for (int ct = 0; ct < 8; ct++) {
            v4f acc0 = {0,0,0,0}, acc1 = {0,0,0,0};
            #pragma unroll
            for (int ch = 0; ch < 4; ch++) {
                v8s bfr = *(const v8s*)&wmat[(ct * 16 + m) * 128 + ch * 32 + quad * 8];
                acc0 = MFMA16(a[0][ch], bfr, acc0);
                acc1 = MFMA16(a[1][ch], bfr, acc1);
            }
            int col = ct * 16 + m;
            float bcol = bias[col];
            if (o < 2) {
                #pragma unroll
                for (int r = 0; r < 4; r++) {
                    int row0 = w * 32 + quad * 4 + r;
                    tls[row0 * 136 + col]        = f2bf(acc0[r] + bcol);
                    tls[(row0 + 16) * 136 + col] = f2bf(acc1[r] + bcol);
                }
            } else {
                #pragma unroll
                for (int r = 0; r < 4; r++) {
                    int row0 = w * 32 + quad * 4 + r;
                    tls[col * 136 + row0]      = f2bf(acc0[r] + bcol);
                    tls[col * 136 + row0 + 16] = f2bf(acc1[r] + bcol);
                }
            }
        }
        __syncthreads();
        if (o < 2) {
            us* dst = (o == 0 ? Q : K) + (size_t)b * SEQ * CCH;
            #pragma unroll
            for (int rep = 0; rep < 8; rep++) {
                int idx = rep * 256 + tid;
                int row = idx >> 4, chunk = idx & 15;
                *(v8s*)&dst[(size_t)(s0 + row) * 128 + chunk * 8] =
                    *(const v8s*)&tls[row * 136 + chunk * 8];
            }
        } else {
            us* vdst = Vt + (size_t)b * CCH * SEQ;
            #pragma unroll
            for (int rep = 0; rep < 8; rep++) {
                int idx = rep * 256 + tid;
                int c = idx >> 4, chunk = idx & 15;
                *(v8s*)&vdst[(size_t)c * SEQ + s0 + chunk * 8] =
                    *(const v8s*)&tls[c * 136 + chunk * 8];
            }
        }
        __syncthreads();
    }
}

// ---- flash attention + fused out-projection + residual ---------------------
// grid: 512 = 64 batches x 8 q-tiles of 128 rows; XCD-swizzled (8 batches/XCD
// -> K+V = 4MB = one L2). Block 256 (4 waves); wave owns 32 Q rows. K/V tiles
// staged per block via global_load_lds (XOR-chunk swizzle). After the K-loop
// the block holds the complete O tile (128s x 128ch) in registers: it is
// round-tripped through the dead k/v LDS region and projected (out^T = wo*O^T)
// with bias+residual, storing fp32 directly to out[b][c][s]. No O in HBM.
__global__ __launch_bounds__(256, 3) void attn_kernel(
    const us* __restrict__ Q, const us* __restrict__ K,
    const us* __restrict__ Vt, const us* __restrict__ wbo,
    const float* __restrict__ bo, const float* __restrict__ x,
    float* __restrict__ out)
{
    __shared__ char smem_raw[51200];
    us* klds = (us*)smem_raw;                    // 64x128, chunk^=(key&15)
    us* vlds = (us*)(smem_raw + 16384);          // 128x64, chunk^=(ch&7)
    us* plds = (us*)(smem_raw + 32768);          // 4 waves x 32x72
    us* olds = (us*)smem_raw;                    // epilogue: 128x136 (34816 B)

    int i = blockIdx.x;
    int b  = (i & 7) * 8 + ((i >> 3) & 7);       // 8 batches per XCD
    int qt = i >> 6;                             // 0..7
    int tid = threadIdx.x;
    int w = tid >> 6, lane = tid & 63;
    int m = lane & 15, quad = lane >> 4;
    int qrow0 = qt * 128 + w * 32;
    const us* Qb = Q + (size_t)b * SEQ * CCH;
    const us* Kb = K + (size_t)b * SEQ * CCH;
    const us* Vb = Vt + (size_t)b * CCH * SEQ;
    us* pw = plds + w * 32 * 72;

    // persistent Q A-frags: 2 stripes x 4 ch-chunks
    v8s aq[2][4];
    #pragma unroll
    for (int st = 0; st < 2; st++)
        #pragma unroll
        for (int ch = 0; ch < 4; ch++)
            aq[st][ch] = *(const v8s*)&Qb[(size_t)(qrow0 + st * 16 + m) * 128 + ch * 32 + quad * 8];

    v4f oacc[2][8];
    #pragma unroll
    for (int st = 0; st < 2; st++)
        #pragma unroll
        for (int ct = 0; ct < 8; ct++) oacc[st][ct] = (v4f){0, 0, 0, 0};
    float lrun[2][4] = {{0.f,0.f,0.f,0.f},{0.f,0.f,0.f,0.f}};

    // staging pointers, hoisted (advance: K += 8192, V += 64 per tile)
    const us* kg[4]; const us* vg[4];
    #pragma unroll
    for (int j4 = 0; j4 < 4; j4++) {
        int j = w * 4 + j4;
        int kr = 4 * j + (lane >> 4);
        kg[j4] = Kb + (size_t)kr * 128 + ((lane & 15) ^ (kr & 15)) * 8;
        int vc = 8 * j + (lane >> 3);
        vg[j4] = Vb + (size_t)vc * SEQ + ((lane & 7) ^ (vc & 7)) * 8;
    }

    for (int kt = 0; kt < 16; kt++) {
        __syncthreads();                         // prev tile fully consumed
        #pragma unroll
        for (int j4 = 0; j4 < 4; j4++) {
            int j = w * 4 + j4;
            gld_lds16(kg[j4] + kt * 8192, klds + j * 512);
            gld_lds16(vg[j4] + kt * 64,   vlds + j * 512);
        }
        __syncthreads();                         // staging complete

        // ---- QK^T: 4 key 16-tiles x 2 stripes ----
        #pragma unroll
        for (int c2 = 0; c2 < 4; c2++) {
            int krow = c2 * 16 + m;
            v4f acc0 = {0,0,0,0}, acc1 = {0,0,0,0};
            #pragma unroll
            for (int ch = 0; ch < 4; ch++) {
                int chunk = (ch * 4 + quad) ^ (krow & 15);
                v8s kb = *(const v8s*)&klds[krow * 128 + chunk * 8];
                acc0 = MFMA16(aq[0][ch], kb, acc0);
                acc1 = MFMA16(aq[1][ch], kb, acc1);
            }
            #pragma unroll
            for (int r = 0; r < 4; r++) {
                float p0 = __expf(acc0[r] * SCALEV);
                float p1 = __expf(acc1[r] * SCALEV);
                lrun[0][r] += p0;
                lrun[1][r] += p1;
                pw[(quad * 4 + r) * 72 + c2 * 16 + m]      = f2bf(p0);
                pw[(16 + quad * 4 + r) * 72 + c2 * 16 + m] = f2bf(p1);
            }
        }
        // ---- P: C-layout -> A-frags (wave-local LDS, in-order) ----
        v8s pa[2][2];
        #pragma unroll
        for (int st = 0; st < 2; st++)
            #pragma unroll
            for (int kc2 = 0; kc2 < 2; kc2++)
                pa[st][kc2] = *(const v8s*)&pw[(st * 16 + m) * 72 + kc2 * 32 + quad * 8];
        // ---- PV: 8 out-col tiles x 2 k-chunks x 2 stripes ----
        #pragma unroll
        for (int ct = 0; ct < 8; ct++) {
            int vrow = ct * 16 + m;
            #pragma unroll
            for (int kc2 = 0; kc2 < 2; kc2++) {
                int chunk = (kc2 * 4 + quad) ^ (vrow & 7);
                v8s vb = *(const v8s*)&vlds[vrow * 64 + chunk * 8];
                oacc[0][ct] = MFMA16(pa[0][kc2], vb, oacc[0][ct]);
                oacc[1][ct] = MFMA16(pa[1][kc2], vb, oacc[1][ct]);
            }
        }
    }
    // ---- row-sum reduce (once) ----
    float inv[2][4];
    #pragma unroll
    for (int st = 0; st < 2; st++)
        #pragma unroll
        for (int r = 0; r < 4; r++) {
            float rs = lrun[st][r];
            rs += __shfl_xor(rs, 1);
            rs += __shfl_xor(rs, 2);
            rs += __shfl_xor(rs, 4);
            rs += __shfl_xor(rs, 8);
            inv[st][r] = 1.0f / rs;
        }
    __syncthreads();                             // k/v/p LDS dead; reuse as olds
    // ---- O tile (normalized bf16) -> LDS [s][ch], pitch 136 ----
    #pragma unroll
    for (int st = 0; st < 2; st++)
        #pragma unroll
        for (int ct = 0; ct < 8; ct++)
            #pragma unroll
            for (int r = 0; r < 4; r++)
                olds[(w * 32 + st * 16 + quad * 4 + r) * 136 + ct * 16 + m] =
                    f2bf(oacc[st][ct][r] * inv[st][r]);
    __syncthreads();
    // ---- projection: out^T[c][s] = wo @ O^T, + bias + residual ----
    const float* xb = x + (size_t)b * CCH * SEQ;
    float* ob = out + (size_t)b * CCH * SEQ;
    int sbase = qt * 128 + w * 32;
    v8s obf[2][4];
    #pragma unroll
    for (int st = 0; st < 2; st++)
        #pragma unroll
        for (int ch = 0; ch < 4; ch++)
            obf[st][ch] = *(const v8s*)&olds[(w * 32 + st * 16 + m) * 136 + ch * 32 + quad * 8];
    #pragma unroll
    for (int mt = 0; mt < 8; mt++) {
        v8s af[4];
        #pragma unroll
        for (int ch = 0; ch < 4; ch++)
            af[ch] = *(const v8s*)&wbo[(mt * 16 + m) * 128 + ch * 32 + quad * 8];
        #pragma unroll
        for (int st = 0; st < 2; st++) {
            v4f acc = {0,0,0,0};
            #pragma unroll
            for (int ch = 0; ch < 4; ch++)
                acc = MFMA16(af[ch], obf[st][ch], acc);
            #pragma unroll
            for (int r = 0; r < 4; r++) {
                int c = mt * 16 + quad * 4 + r;
                int idx = c * SEQ + sbase + st * 16 + m;
                ob[idx] = acc[r] + bo[c] + xb[idx];
            }
        }
    }
}

extern "C" void kernel_launch(void* const* d_in, const int* in_sizes, int n_in,
                              void* d_out, int out_size, void* d_ws, size_t ws_size,
                              hipStream_t stream) {
    const float* x    = (const float*)d_in[0];
    const float* gn_w = (const float*)d_in[1];
    const float* gn_b = (const float*)d_in[2];
    const float* wq   = (const float*)d_in[3];
    const float* bq   = (const float*)d_in[4];
    const float* wk   = (const float*)d_in[5];
    const float* bk   = (const float*)d_in[6];
    const float* wv   = (const float*)d_in[7];
    const float* bv   = (const float*)d_in[8];
    const float* wo   = (const float*)d_in[9];
    const float* bo   = (const float*)d_in[10];
    float* out = (float*)d_out;

    char* ws = (char*)d_ws;
    us* wbf      = (us*)ws;
    float* meanr = (float*)(ws + 131072);
    float* rstdr = (float*)(ws + 139264);
    us* Qbuf     = (us*)(ws + 147456);
    us* Kbuf     = (us*)(ws + 147456 + 16777216ull);
    us* Vtbuf    = (us*)(ws + 147456 + 2ull * 16777216ull);

    prep_gn<<<256 + BATCH * NG, 256, 0, stream>>>(wq, wk, wv, wo, wbf, x, meanr, rstdr);
    qkv_kernel<<<BATCH * 8, 256, 0, stream>>>(x, gn_w, gn_b, meanr, rstdr, wbf,
                                              bq, bk, bv, Qbuf, Kbuf, Vtbuf);
    attn_kernel<<<512, 256, 0, stream>>>(Qbuf, Kbuf, Vtbuf, wbf + 3 * 16384,
                                         bo, x, out);
}

// Round 7
// 191.964 us; speedup vs baseline: 1.1797x; 1.0850x over previous
//
#include <hip/hip_runtime.h>
#include <hip/hip_bf16.h>

#define BATCH 64
#define CCH 128
#define SEQ 1024
#define NG 32
#define EPSV 1e-6f
#define SCALEV 0.044194173824159216f

typedef short v8s __attribute__((ext_vector_type(8)));
typedef short v4s __attribute__((ext_vector_type(4)));
typedef float v4f __attribute__((ext_vector_type(4)));
typedef unsigned short us;

__device__ __forceinline__ us f2bf(float f) {
    __hip_bfloat16 h = __float2bfloat16(f);
    return *reinterpret_cast<us*>(&h);
}

#define MFMA16(a, b, c) __builtin_amdgcn_mfma_f32_16x16x32_bf16(a, b, c, 0, 0, 0)

// async global->LDS, 16B per lane; LDS dst = base + lane*16 (wave-uniform base)
__device__ __forceinline__ void gld_lds16(const us* g, us* l) {
    __builtin_amdgcn_global_load_lds(
        (const __attribute__((address_space(1))) void*)g,
        (__attribute__((address_space(3))) void*)l, 16, 0, 0);
}

// ---------------- fused: weights fp32->bf16 (blocks 0..255) + GN stats ------
__global__ void prep_gn(const float* __restrict__ wq, const float* __restrict__ wk,
                        const float* __restrict__ wv, const float* __restrict__ wo,
                        us* wbf, const float* __restrict__ x,
                        float* meanr, float* rstdr) {
    int tid = threadIdx.x;
    if (blockIdx.x < 256) {
        int i = blockIdx.x * 256 + tid;          // 0..65535
        const float* srcs[4] = {wq, wk, wv, wo};
        wbf[i] = f2bf(srcs[i >> 14][i & 16383]);
        return;
    }
    int bg = blockIdx.x - 256;                   // b*NG + g, 0..2047
    const float4* p = (const float4*)(x + (size_t)bg * (4 * SEQ));
    float s1 = 0.f, s2 = 0.f;
    #pragma unroll
    for (int i = 0; i < 4; i++) {
        float4 v = p[i * 256 + tid];
        s1 += v.x + v.y + v.z + v.w;
        s2 += v.x * v.x + v.y * v.y + v.z * v.z + v.w * v.w;
    }
    #pragma unroll
    for (int off = 32; off; off >>= 1) {
        s1 += __shfl_down(s1, off);
        s2 += __shfl_down(s2, off);
    }
    __shared__ float a1[4], a2[4];
    int w = tid >> 6, l = tid & 63;
    if (l == 0) { a1[w] = s1; a2[w] = s2; }
    __syncthreads();
    if (tid == 0) {
        float t1 = a1[0] + a1[1] + a1[2] + a1[3];
        float t2 = a2[0] + a2[1] + a2[2] + a2[3];
        float mean = t1 * (1.0f / (4 * SEQ));
        float var  = t2 * (1.0f / (4 * SEQ)) - mean * mean;
        meanr[bg] = mean;
        rstdr[bg] = rsqrtf(var + EPSV);
    }
}

// ---------------- fused GroupNorm-apply + QKV projection (v2) ---------------
// grid: 1024 = 64 batches x 16 s-tiles of 64 rows; block 256 (4 waves).
// ONE barrier. Wave w owns 6 of 24 output col-tiles (3 o x 8 ct); its 24
// weight B-frags are loaded once into registers, then 4 s-stripes of shared
// A-frags stream from LDS. Outputs written straight from D-regs: V as packed
// 8B stores (D rows = s contiguous in Vt[c][s]); Q/K as 2B stores whose
// 16-lane groups cover 32B segments (L2 merges; full line coverage per block).
__global__ __launch_bounds__(256, 2) void qkv_kernel(
    const float* __restrict__ x, const float* __restrict__ gn_w,
    const float* __restrict__ gn_b, const float* __restrict__ meanr,
    const float* __restrict__ rstdr, const us* __restrict__ wbf,
    const float* __restrict__ bq, const float* __restrict__ bk,
    const float* __restrict__ bv,
    us* Q, us* K, us* Vt)
{
    __shared__ us tls[64 * 136];                 // x-norm tile [s][c], pitch 136
    int b  = blockIdx.x >> 4;
    int s0 = (blockIdx.x & 15) * 64;
    int tid = threadIdx.x;
    const float* xb = x + (size_t)b * CCH * SEQ;

    for (int rep = 0; rep < 32; rep++) {
        int idx = rep * 256 + tid;
        int c = idx >> 6, s = idx & 63;
        float v = xb[c * SEQ + s0 + s];
        int g = c >> 2;
        float t = (v - meanr[b * NG + g]) * rstdr[b * NG + g] * gn_w[c] + gn_b[c];
        tls[s * 136 + c] = f2bf(t);
    }
    __syncthreads();                             // the only barrier

    int w = tid >> 6, lane = tid & 63;
    int m = lane & 15, quad = lane >> 4;

    // hoisted weight B-frags + biases for this wave's 6 col-tiles
    v8s bfr[6][4];
    float bias[6];
    #pragma unroll
    for (int t = 0; t < 6; t++) {
        int T = w * 6 + t;                       // wave-uniform
        int o = T >> 3, ct = T & 7;
        const us* wmat = wbf + o * 16384;
        #pragma unroll
        for (int ch = 0; ch < 4; ch++)
            bfr[t][ch] = *(const v8s*)&wmat[(ct * 16 + m) * 128 + ch * 32 + quad * 8];
        const float* bb = (o == 0) ? bq : (o == 1) ? bk : bv;
        bias[t] = bb[ct * 16 + m];
    }

    us* Qb = Q + (size_t)b * SEQ * CCH;
    us* Kb = K + (size_t)b * SEQ * CCH;
    us* Vb = Vt + (size_t)b * CCH * SEQ;

    #pragma unroll
    for (int st = 0; st < 4; st++) {
        v8s a[4];
        #pragma unroll
        for (int ch = 0; ch < 4; ch++)
            a[ch] = *(const v8s*)&tls[(st * 16 + m) * 136 + ch * 32 + quad * 8];
        int srow = s0 + st * 16 + quad * 4;
        #pragma unroll
        for (int t = 0; t < 6; t++) {
            int T = w * 6 + t;
            int o = T >> 3, ct = T & 7;
            v4f acc = {0,0,0,0};
            #pragma unroll
            for (int ch = 0; ch < 4; ch++)
                acc = MFMA16(a[ch], bfr[t][ch], acc);
            int col = ct * 16 + m;
            if (o < 2) {
                us* dst = (o == 0) ? Qb : Kb;
                #pragma unroll
                for (int r = 0; r < 4; r++)
                    dst[(size_t)(srow + r) * 128 + col] = f2bf(acc[r] + bias[t]);
            } else {
                v4s pk;
                #pragma unroll
                for (int r = 0; r < 4; r++) pk[r] = (short)f2bf(acc[r] + bias[t]);
                *(v4s*)&Vb[(size_t)col * SEQ + srow] = pk;
            }
        }
    }
}

// ---- flash attention + fused out-projection + residual ---------------------
// grid: 512 = 64 batches x 8 q-tiles of 128 rows; XCD-swizzled (8 batches/XCD
// -> K+V = 4MB = one L2). Block 256 (4 waves); wave owns 32 Q rows. K/V tiles
// staged per block via global_load_lds (XOR-chunk swizzle). After the K-loop
// the block holds the complete O tile (128s x 128ch) in registers: it is
// round-tripped through the dead k/v LDS region and projected (out^T = wo*O^T)
// with bias+residual, storing fp32 directly to out[b][c][s]. No O in HBM.
__global__ __launch_bounds__(256, 3) void attn_kernel(
    const us* __restrict__ Q, const us* __restrict__ K,
    const us* __restrict__ Vt, const us* __restrict__ wbo,
    const float* __restrict__ bo, const float* __restrict__ x,
    float* __restrict__ out)
{
    __shared__ char smem_raw[51200];
    us* klds = (us*)smem_raw;                    // 64x128, chunk^=(key&15)
    us* vlds = (us*)(smem_raw + 16384);          // 128x64, chunk^=(ch&7)
    us* plds = (us*)(smem_raw + 32768);          // 4 waves x 32x72
    us* olds = (us*)smem_raw;                    // epilogue: 128x136 (34816 B)

    int i = blockIdx.x;
    int b  = (i & 7) * 8 + ((i >> 3) & 7);       // 8 batches per XCD
    int qt = i >> 6;                             // 0..7
    int tid = threadIdx.x;
    int w = tid >> 6, lane = tid & 63;
    int m = lane & 15, quad = lane >> 4;
    int qrow0 = qt * 128 + w * 32;
    const us* Qb = Q + (size_t)b * SEQ * CCH;
    const us* Kb = K + (size_t)b * SEQ * CCH;
    const us* Vb = Vt + (size_t)b * CCH * SEQ;
    us* pw = plds + w * 32 * 72;

    v8s aq[2][4];
    #pragma unroll
    for (int st = 0; st < 2; st++)
        #pragma unroll
        for (int ch = 0; ch < 4; ch++)
            aq[st][ch] = *(const v8s*)&Qb[(size_t)(qrow0 + st * 16 + m) * 128 + ch * 32 + quad * 8];

    v4f oacc[2][8];
    #pragma unroll
    for (int st = 0; st < 2; st++)
        #pragma unroll
        for (int ct = 0; ct < 8; ct++) oacc[st][ct] = (v4f){0, 0, 0, 0};
    float lrun[2][4] = {{0.f,0.f,0.f,0.f},{0.f,0.f,0.f,0.f}};

    const us* kg[4]; const us* vg[4];
    #pragma unroll
    for (int j4 = 0; j4 < 4; j4++) {
        int j = w * 4 + j4;
        int kr = 4 * j + (lane >> 4);
        kg[j4] = Kb + (size_t)kr * 128 + ((lane & 15) ^ (kr & 15)) * 8;
        int vc = 8 * j + (lane >> 3);
        vg[j4] = Vb + (size_t)vc * SEQ + ((lane & 7) ^ (vc & 7)) * 8;
    }

    for (int kt = 0; kt < 16; kt++) {
        __syncthreads();
        #pragma unroll
        for (int j4 = 0; j4 < 4; j4++) {
            int j = w * 4 + j4;
            gld_lds16(kg[j4] + kt * 8192, klds + j * 512);
            gld_lds16(vg[j4] + kt * 64,   vlds + j * 512);
        }
        __syncthreads();

        #pragma unroll
        for (int c2 = 0; c2 < 4; c2++) {
            int krow = c2 * 16 + m;
            v4f acc0 = {0,0,0,0}, acc1 = {0,0,0,0};
            #pragma unroll
            for (int ch = 0; ch < 4; ch++) {
                int chunk = (ch * 4 + quad) ^ (krow & 15);
                v8s kb = *(const v8s*)&klds[krow * 128 + chunk * 8];
                acc0 = MFMA16(aq[0][ch], kb, acc0);
                acc1 = MFMA16(aq[1][ch], kb, acc1);
            }
            #pragma unroll
            for (int r = 0; r < 4; r++) {
                float p0 = __expf(acc0[r] * SCALEV);
                float p1 = __expf(acc1[r] * SCALEV);
                lrun[0][r] += p0;
                lrun[1][r] += p1;
                pw[(quad * 4 + r) * 72 + c2 * 16 + m]      = f2bf(p0);
                pw[(16 + quad * 4 + r) * 72 + c2 * 16 + m] = f2bf(p1);
            }
        }
        v8s pa[2][2];
        #pragma unroll
        for (int st = 0; st < 2; st++)
            #pragma unroll
            for (int kc2 = 0; kc2 < 2; kc2++)
                pa[st][kc2] = *(const v8s*)&pw[(st * 16 + m) * 72 + kc2 * 32 + quad * 8];
        #pragma unroll
        for (int ct = 0; ct < 8; ct++) {
            int vrow = ct * 16 + m;
            #pragma unroll
            for (int kc2 = 0; kc2 < 2; kc2++) {
                int chunk = (kc2 * 4 + quad) ^ (vrow & 7);
                v8s vb = *(const v8s*)&vlds[vrow * 64 + chunk * 8];
                oacc[0][ct] = MFMA16(pa[0][kc2], vb, oacc[0][ct]);
                oacc[1][ct] = MFMA16(pa[1][kc2], vb, oacc[1][ct]);
            }
        }
    }
    float inv[2][4];
    #pragma unroll
    for (int st = 0; st < 2; st++)
        #pragma unroll
        for (int r = 0; r < 4; r++) {
            float rs = lrun[st][r];
            rs += __shfl_xor(rs, 1);
            rs += __shfl_xor(rs, 2);
            rs += __shfl_xor(rs, 4);
            rs += __shfl_xor(rs, 8);
            inv[st][r] = 1.0f / rs;
        }
    __syncthreads();                             // k/v/p LDS dead; reuse as olds
    #pragma unroll
    for (int st = 0; st < 2; st++)
        #pragma unroll
        for (int ct = 0; ct < 8; ct++)
            #pragma unroll
            for (int r = 0; r < 4; r++)
                olds[(w * 32 + st * 16 + quad * 4 + r) * 136 + ct * 16 + m] =
                    f2bf(oacc[st][ct][r] * inv[st][r]);
    __syncthreads();
    const float* xb = x + (size_t)b * CCH * SEQ;
    float* ob = out + (size_t)b * CCH * SEQ;
    int sbase = qt * 128 + w * 32;
    v8s obf[2][4];
    #pragma unroll
    for (int st = 0; st < 2; st++)
        #pragma unroll
        for (int ch = 0; ch < 4; ch++)
            obf[st][ch] = *(const v8s*)&olds[(w * 32 + st * 16 + m) * 136 + ch * 32 + quad * 8];
    #pragma unroll
    for (int mt = 0; mt < 8; mt++) {
        v8s af[4];
        #pragma unroll
        for (int ch = 0; ch < 4; ch++)
            af[ch] = *(const v8s*)&wbo[(mt * 16 + m) * 128 + ch * 32 + quad * 8];
        #pragma unroll
        for (int st = 0; st < 2; st++) {
            v4f acc = {0,0,0,0};
            #pragma unroll
            for (int ch = 0; ch < 4; ch++)
                acc = MFMA16(af[ch], obf[st][ch], acc);
            #pragma unroll
            for (int r = 0; r < 4; r++) {
                int c = mt * 16 + quad * 4 + r;
                int idx = c * SEQ + sbase + st * 16 + m;
                ob[idx] = acc[r] + bo[c] + xb[idx];
            }
        }
    }
}

extern "C" void kernel_launch(void* const* d_in, const int* in_sizes, int n_in,
                              void* d_out, int out_size, void* d_ws, size_t ws_size,
                              hipStream_t stream) {
    const float* x    = (const float*)d_in[0];
    const float* gn_w = (const float*)d_in[1];
    const float* gn_b = (const float*)d_in[2];
    const float* wq   = (const float*)d_in[3];
    const float* bq   = (const float*)d_in[4];
    const float* wk   = (const float*)d_in[5];
    const float* bk   = (const float*)d_in[6];
    const float* wv   = (const float*)d_in[7];
    const float* bv   = (const float*)d_in[8];
    const float* wo   = (const float*)d_in[9];
    const float* bo   = (const float*)d_in[10];
    float* out = (float*)d_out;

    char* ws = (char*)d_ws;
    us* wbf      = (us*)ws;
    float* meanr = (float*)(ws + 131072);
    float* rstdr = (float*)(ws + 139264);
    us* Qbuf     = (us*)(ws + 147456);
    us* Kbuf     = (us*)(ws + 147456 + 16777216ull);
    us* Vtbuf    = (us*)(ws + 147456 + 2ull * 16777216ull);

    prep_gn<<<256 + BATCH * NG, 256, 0, stream>>>(wq, wk, wv, wo, wbf, x, meanr, rstdr);
    qkv_kernel<<<1024, 256, 0, stream>>>(x, gn_w, gn_b, meanr, rstdr, wbf,
                                         bq, bk, bv, Qbuf, Kbuf, Vtbuf);
    attn_kernel<<<512, 256, 0, stream>>>(Qbuf, Kbuf, Vtbuf, wbf + 3 * 16384,
                                         bo, x, out);
}

// Round 8
// 181.000 us; speedup vs baseline: 1.2512x; 1.0606x over previous
//
#include <hip/hip_runtime.h>
#include <hip/hip_bf16.h>

#define BATCH 64
#define CCH 128
#define SEQ 1024
#define NG 32
#define EPSV 1e-6f
#define SCALEV 0.044194173824159216f

typedef short v8s __attribute__((ext_vector_type(8)));
typedef short v4s __attribute__((ext_vector_type(4)));
typedef float v4f __attribute__((ext_vector_type(4)));
typedef int   v4i __attribute__((ext_vector_type(4)));
typedef unsigned short us;

__device__ __forceinline__ us f2bf(float f) {
    __hip_bfloat16 h = __float2bfloat16(f);
    return *reinterpret_cast<us*>(&h);
}

#define MFMA16(a, b, c) __builtin_amdgcn_mfma_f32_16x16x32_bf16(a, b, c, 0, 0, 0)

// async global->LDS, 16B per lane; LDS dst = base + lane*16 (wave-uniform base)
__device__ __forceinline__ void gld_lds16(const us* g, us* l) {
    __builtin_amdgcn_global_load_lds(
        (const __attribute__((address_space(1))) void*)g,
        (__attribute__((address_space(3))) void*)l, 16, 0, 0);
}

// ---------------- fused: weights fp32->bf16 (blocks 0..255) + GN stats ------
__global__ void prep_gn(const float* __restrict__ wq, const float* __restrict__ wk,
                        const float* __restrict__ wv, const float* __restrict__ wo,
                        us* wbf, const float* __restrict__ x,
                        float* meanr, float* rstdr) {
    int tid = threadIdx.x;
    if (blockIdx.x < 256) {
        int i = blockIdx.x * 256 + tid;          // 0..65535
        const float* srcs[4] = {wq, wk, wv, wo};
        wbf[i] = f2bf(srcs[i >> 14][i & 16383]);
        return;
    }
    int bg = blockIdx.x - 256;                   // b*NG + g, 0..2047
    const float4* p = (const float4*)(x + (size_t)bg * (4 * SEQ));
    float s1 = 0.f, s2 = 0.f;
    #pragma unroll
    for (int i = 0; i < 4; i++) {
        float4 v = p[i * 256 + tid];
        s1 += v.x + v.y + v.z + v.w;
        s2 += v.x * v.x + v.y * v.y + v.z * v.z + v.w * v.w;
    }
    #pragma unroll
    for (int off = 32; off; off >>= 1) {
        s1 += __shfl_down(s1, off);
        s2 += __shfl_down(s2, off);
    }
    __shared__ float a1[4], a2[4];
    int w = tid >> 6, l = tid & 63;
    if (l == 0) { a1[w] = s1; a2[w] = s2; }
    __syncthreads();
    if (tid == 0) {
        float t1 = a1[0] + a1[1] + a1[2] + a1[3];
        float t2 = a2[0] + a2[1] + a2[2] + a2[3];
        float mean = t1 * (1.0f / (4 * SEQ));
        float var  = t2 * (1.0f / (4 * SEQ)) - mean * mean;
        meanr[bg] = mean;
        rstdr[bg] = rsqrtf(var + EPSV);
    }
}

// ---------------- fused GroupNorm-apply + QKV projection (unchanged R7) -----
__global__ __launch_bounds__(256, 2) void qkv_kernel(
    const float* __restrict__ x, const float* __restrict__ gn_w,
    const float* __restrict__ gn_b, const float* __restrict__ meanr,
    const float* __restrict__ rstdr, const us* __restrict__ wbf,
    const float* __restrict__ bq, const float* __restrict__ bk,
    const float* __restrict__ bv,
    us* Q, us* K, us* Vt)
{
    __shared__ us tls[64 * 136];                 // x-norm tile [s][c], pitch 136
    int b  = blockIdx.x >> 4;
    int s0 = (blockIdx.x & 15) * 64;
    int tid = threadIdx.x;
    const float* xb = x + (size_t)b * CCH * SEQ;

    for (int rep = 0; rep < 32; rep++) {
        int idx = rep * 256 + tid;
        int c = idx >> 6, s = idx & 63;
        float v = xb[c * SEQ + s0 + s];
        int g = c >> 2;
        float t = (v - meanr[b * NG + g]) * rstdr[b * NG + g] * gn_w[c] + gn_b[c];
        tls[s * 136 + c] = f2bf(t);
    }
    __syncthreads();                             // the only barrier

    int w = tid >> 6, lane = tid & 63;
    int m = lane & 15, quad = lane >> 4;

    v8s bfr[6][4];
    float bias[6];
    #pragma unroll
    for (int t = 0; t < 6; t++) {
        int T = w * 6 + t;
        int o = T >> 3, ct = T & 7;
        const us* wmat = wbf + o * 16384;
        #pragma unroll
        for (int ch = 0; ch < 4; ch++)
            bfr[t][ch] = *(const v8s*)&wmat[(ct * 16 + m) * 128 + ch * 32 + quad * 8];
        const float* bb = (o == 0) ? bq : (o == 1) ? bk : bv;
        bias[t] = bb[ct * 16 + m];
    }

    us* Qb = Q + (size_t)b * SEQ * CCH;
    us* Kb = K + (size_t)b * SEQ * CCH;
    us* Vb = Vt + (size_t)b * CCH * SEQ;

    #pragma unroll
    for (int st = 0; st < 4; st++) {
        v8s a[4];
        #pragma unroll
        for (int ch = 0; ch < 4; ch++)
            a[ch] = *(const v8s*)&tls[(st * 16 + m) * 136 + ch * 32 + quad * 8];
        int srow = s0 + st * 16 + quad * 4;
        #pragma unroll
        for (int t = 0; t < 6; t++) {
            int T = w * 6 + t;
            int o = T >> 3, ct = T & 7;
            v4f acc = {0,0,0,0};
            #pragma unroll
            for (int ch = 0; ch < 4; ch++)
                acc = MFMA16(a[ch], bfr[t][ch], acc);
            int col = ct * 16 + m;
            if (o < 2) {
                us* dst = (o == 0) ? Qb : Kb;
                #pragma unroll
                for (int r = 0; r < 4; r++)
                    dst[(size_t)(srow + r) * 128 + col] = f2bf(acc[r] + bias[t]);
            } else {
                v4s pk;
                #pragma unroll
                for (int r = 0; r < 4; r++) pk[r] = (short)f2bf(acc[r] + bias[t]);
                *(v4s*)&Vb[(size_t)col * SEQ + srow] = pk;
            }
        }
    }
}

// ---- flash attention + fused out-projection, NO P-LDS (bpermute transpose) -
// grid: 1024 = 64 batches x 16 q-tiles of 64 rows; XCD-swizzled (8 batch/XCD).
// Block 128 (2 waves); wave owns 32 Q rows. K/V staged via global_load_lds
// (XOR-chunk swizzle). QK computed transposed (S^T = K*Q^T) so scores land
// with col=q=lane&15; exp'd P is moved to PV A-frag layout with in-register
// __shfl (ds_bpermute) on packed bf16 pairs — zero LDS for P. 32.7KB LDS ->
// 4+ blocks/CU co-resident.
__global__ __launch_bounds__(128, 2) void attn_kernel(
    const us* __restrict__ Q, const us* __restrict__ K,
    const us* __restrict__ Vt, const us* __restrict__ wbo,
    const float* __restrict__ bo, const float* __restrict__ x,
    float* __restrict__ out)
{
    __shared__ char smem_raw[32768];
    us* klds = (us*)smem_raw;                    // 64x128, chunk^=(key&15)
    us* vlds = (us*)(smem_raw + 16384);          // 128x64, chunk^=(ch&7)
    us* olds = (us*)smem_raw;                    // epilogue: 64x136 = 17408 B

    int i = blockIdx.x;
    int b  = (i & 7) * 8 + ((i >> 3) & 7);       // 8 batches per XCD
    int qt = i >> 6;                             // 0..15
    int tid = threadIdx.x;
    int w = tid >> 6, lane = tid & 63;           // w in {0,1}
    int m = lane & 15, quad = lane >> 4;
    int qrow0 = qt * 64 + w * 32;
    const us* Qb = Q + (size_t)b * SEQ * CCH;
    const us* Kb = K + (size_t)b * SEQ * CCH;
    const us* Vb = Vt + (size_t)b * CCH * SEQ;

    // Q as B-frags of Q^T (addressing identical to A-frag of Q)
    v8s aq[2][4];
    #pragma unroll
    for (int st = 0; st < 2; st++)
        #pragma unroll
        for (int ch = 0; ch < 4; ch++)
            aq[st][ch] = *(const v8s*)&Qb[(size_t)(qrow0 + st * 16 + m) * 128 + ch * 32 + quad * 8];

    v4f oacc[2][8];
    #pragma unroll
    for (int st = 0; st < 2; st++)
        #pragma unroll
        for (int ct = 0; ct < 8; ct++) oacc[st][ct] = (v4f){0, 0, 0, 0};
    float lrun[2] = {0.f, 0.f};                  // per-lane: sum over this
                                                 // lane's keys for q = m

    // staging pointers: wave w stages insts j = w*8 + j8
    const us* kg[8]; const us* vg[8];
    #pragma unroll
    for (int j8 = 0; j8 < 8; j8++) {
        int j = w * 8 + j8;
        int kr = 4 * j + (lane >> 4);
        kg[j8] = Kb + (size_t)kr * 128 + ((lane & 15) ^ (kr & 15)) * 8;
        int vc = 8 * j + (lane >> 3);
        vg[j8] = Vb + (size_t)vc * SEQ + ((lane & 7) ^ (vc & 7)) * 8;
    }
    int idx0 = 2 * (quad & 1) * 16 + m;          // bpermute source lanes
    int idx1 = idx0 + 16;

    for (int kt = 0; kt < 16; kt++) {
        __syncthreads();                         // prev tile fully consumed
        #pragma unroll
        for (int j8 = 0; j8 < 8; j8++) {
            int j = w * 8 + j8;
            gld_lds16(kg[j8] + kt * 8192, klds + j * 512);
            gld_lds16(vg[j8] + kt * 64,   vlds + j * 512);
        }
        __syncthreads();                         // staging complete

        // ---- S^T = K*Q^T : 4 key 16-tiles x 2 stripes; exp + pack bf16x2 ---
        int e[2][4][2];
        #pragma unroll
        for (int c2 = 0; c2 < 4; c2++) {
            int krow = c2 * 16 + m;              // lane m = key-within-tile
            v4f acc0 = {0,0,0,0}, acc1 = {0,0,0,0};
            #pragma unroll
            for (int ch = 0; ch < 4; ch++) {
                int chunk = (ch * 4 + quad) ^ (krow & 15);
                v8s kb = *(const v8s*)&klds[krow * 128 + chunk * 8];
                acc0 = MFMA16(kb, aq[0][ch], acc0);   // A=K, B=Q^T
                acc1 = MFMA16(kb, aq[1][ch], acc1);
            }
            float p0[4], p1[4];
            #pragma unroll
            for (int r = 0; r < 4; r++) {
                p0[r] = __expf(acc0[r] * SCALEV);
                p1[r] = __expf(acc1[r] * SCALEV);
                lrun[0] += p0[r];
                lrun[1] += p1[r];
            }
            e[0][c2][0] = (int)f2bf(p0[0]) | ((int)f2bf(p0[1]) << 16);
            e[0][c2][1] = (int)f2bf(p0[2]) | ((int)f2bf(p0[3]) << 16);
            e[1][c2][0] = (int)f2bf(p1[0]) | ((int)f2bf(p1[1]) << 16);
            e[1][c2][1] = (int)f2bf(p1[2]) | ((int)f2bf(p1[3]) << 16);
        }
        // ---- P -> A-frag layout via in-register bpermute ----
        v8s pa[2][2];
        #pragma unroll
        for (int st = 0; st < 2; st++)
            #pragma unroll
            for (int kc2 = 0; kc2 < 2; kc2++) {
                int c0 = (quad < 2) ? e[st][2 * kc2][0] : e[st][2 * kc2 + 1][0];
                int c1 = (quad < 2) ? e[st][2 * kc2][1] : e[st][2 * kc2 + 1][1];
                v4i t;
                t[0] = __shfl(c0, idx0);
                t[1] = __shfl(c1, idx0);
                t[2] = __shfl(c0, idx1);
                t[3] = __shfl(c1, idx1);
                pa[st][kc2] = __builtin_bit_cast(v8s, t);
            }
        // ---- PV: 8 out-col tiles x 2 k-chunks x 2 stripes ----
        #pragma unroll
        for (int ct = 0; ct < 8; ct++) {
            int vrow = ct * 16 + m;
            #pragma unroll
            for (int kc2 = 0; kc2 < 2; kc2++) {
                int chunk = (kc2 * 4 + quad) ^ (vrow & 7);
                v8s vb = *(const v8s*)&vlds[vrow * 64 + chunk * 8];
                oacc[0][ct] = MFMA16(pa[0][kc2], vb, oacc[0][ct]);
                oacc[1][ct] = MFMA16(pa[1][kc2], vb, oacc[1][ct]);
            }
        }
    }
    // ---- row sums: reduce lane partials across quads (q = m per lane) ----
    float inv[2][4];
    #pragma unroll
    for (int st = 0; st < 2; st++) {
        float rs = lrun[st];
        rs += __shfl_xor(rs, 16);
        rs += __shfl_xor(rs, 32);                // rs = rowsum(q = m)
        #pragma unroll
        for (int r = 0; r < 4; r++)
            inv[st][r] = 1.0f / __shfl(rs, quad * 4 + r);
    }
    __syncthreads();                             // k/v LDS dead; reuse as olds
    #pragma unroll
    for (int st = 0; st < 2; st++)
        #pragma unroll
        for (int ct = 0; ct < 8; ct++)
            #pragma unroll
            for (int r = 0; r < 4; r++)
                olds[(w * 32 + st * 16 + quad * 4 + r) * 136 + ct * 16 + m] =
                    f2bf(oacc[st][ct][r] * inv[st][r]);
    __syncthreads();
    // ---- projection: out^T[c][s] = wo @ O^T, + bias + residual ----
    const float* xb = x + (size_t)b * CCH * SEQ;
    float* ob = out + (size_t)b * CCH * SEQ;
    int sbase = qt * 64 + w * 32;
    v8s obf[2][4];
    #pragma unroll
    for (int st = 0; st < 2; st++)
        #pragma unroll
        for (int ch = 0; ch < 4; ch++)
            obf[st][ch] = *(const v8s*)&olds[(w * 32 + st * 16 + m) * 136 + ch * 32 + quad * 8];
    #pragma unroll
    for (int mt = 0; mt < 8; mt++) {
        v8s af[4];
        #pragma unroll
        for (int ch = 0; ch < 4; ch++)
            af[ch] = *(const v8s*)&wbo[(mt * 16 + m) * 128 + ch * 32 + quad * 8];
        #pragma unroll
        for (int st = 0; st < 2; st++) {
            v4f acc = {0,0,0,0};
            #pragma unroll
            for (int ch = 0; ch < 4; ch++)
                acc = MFMA16(af[ch], obf[st][ch], acc);
            #pragma unroll
            for (int r = 0; r < 4; r++) {
                int c = mt * 16 + quad * 4 + r;
                int idx = c * SEQ + sbase + st * 16 + m;
                ob[idx] = acc[r] + bo[c] + xb[idx];
            }
        }
    }
}

extern "C" void kernel_launch(void* const* d_in, const int* in_sizes, int n_in,
                              void* d_out, int out_size, void* d_ws, size_t ws_size,
                              hipStream_t stream) {
    const float* x    = (const float*)d_in[0];
    const float* gn_w = (const float*)d_in[1];
    const float* gn_b = (const float*)d_in[2];
    const float* wq   = (const float*)d_in[3];
    const float* bq   = (const float*)d_in[4];
    const float* wk   = (const float*)d_in[5];
    const float* bk   = (const float*)d_in[6];
    const float* wv   = (const float*)d_in[7];
    const float* bv   = (const float*)d_in[8];
    const float* wo   = (const float*)d_in[9];
    const float* bo   = (const float*)d_in[10];
    float* out = (float*)d_out;

    char* ws = (char*)d_ws;
    us* wbf      = (us*)ws;
    float* meanr = (float*)(ws + 131072);
    float* rstdr = (float*)(ws + 139264);
    us* Qbuf     = (us*)(ws + 147456);
    us* Kbuf     = (us*)(ws + 147456 + 16777216ull);
    us* Vtbuf    = (us*)(ws + 147456 + 2ull * 16777216ull);

    prep_gn<<<256 + BATCH * NG, 256, 0, stream>>>(wq, wk, wv, wo, wbf, x, meanr, rstdr);
    qkv_kernel<<<1024, 256, 0, stream>>>(x, gn_w, gn_b, meanr, rstdr, wbf,
                                         bq, bk, bv, Qbuf, Kbuf, Vtbuf);
    attn_kernel<<<1024, 128, 0, stream>>>(Qbuf, Kbuf, Vtbuf, wbf + 3 * 16384,
                                          bo, x, out);
}